// Round 17
// baseline (153.895 us; speedup 1.0000x reference)
//
#include <hip/hip_runtime.h>
#include <hip/hip_bf16.h>
#include <stdint.h>

#define E_EDGES 262144
#define DFEAT 256
#define KDIM 512
#define NNODES 131072

typedef __attribute__((ext_vector_type(8))) short short8;
typedef __attribute__((ext_vector_type(4))) float f32x4;

static __device__ __forceinline__ unsigned f2bf(float x) {
    unsigned u = __float_as_uint(x);
    u += 0x7fffu + ((u >> 16) & 1u);   // RNE
    return u >> 16;
}
static __device__ __forceinline__ float bf2f(unsigned short s) {
    return __uint_as_float(((unsigned)s) << 16);
}
static __device__ __forceinline__ f32x4 nt_load4(const float* p) {
    return __builtin_nontemporal_load((const f32x4*)p);
}

// ===================== fast path =====================
// wB2: k-slab-major repack (proven R9). wB2[((k>>3)*512 + n)*8 + (k&7)]
__global__ __launch_bounds__(256) void prep_wB2_kernel(const float* __restrict__ W1,
                                                       unsigned short* __restrict__ wB2) {
    int idx = blockIdx.x * 256 + threadIdx.x;   // 131072
    int n = idx >> 8;
    int k = idx & 255;
    int srow = k + ((n >= 256) ? 256 : 0);
    wB2[((size_t)(k >> 3) * 512 + n) * 8 + (k & 7)] = (unsigned short)f2bf(W1[srow * 256 + (n & 255)]);
}

// Persistent-pipeline GEMM (R12 config, proven) + NON-TEMPORAL TABLE LOADS:
// table is read-once (no reuse) -> keep it OUT of L3 so uv (written with
// regular allocate-stores) stays L3-resident for the edge pass.
__global__ __launch_bounds__(512, 2) void gemm_uv5_kernel(const float* __restrict__ table,
                                                          const unsigned short* __restrict__ wB2,
                                                          unsigned short* __restrict__ uv) {
    __shared__ __align__(16) unsigned char lds[65536];

    const int tid = threadIdx.x;
    const int l = tid & 63;
    const int wv = tid >> 6;
    const int l15 = l & 15;
    const int lq = l >> 4;

    short8 bfr[8][4];
#pragma unroll
    for (int kk = 0; kk < 8; ++kk)
#pragma unroll
        for (int j = 0; j < 4; ++j) {
            int col = wv * 64 + j * 16 + l15;
            bfr[kk][j] = *(const short8*)(wB2 + ((size_t)(kk * 4 + lq) * 512 + col) * 8);
        }

    const int srow = tid >> 4;
    const int gc0 = (tid & 15) * 2;
    const int tile0 = blockIdx.x * 8;

    f32x4 sreg[4];
    auto loadA = [&](int t) {
        const float* src = table + (size_t)(tile0 + t) * 32 * DFEAT + (size_t)srow * DFEAT;
#pragma unroll
        for (int m = 0; m < 2; ++m) {
            sreg[m * 2]     = nt_load4(src + (gc0 + m) * 8);
            sreg[m * 2 + 1] = nt_load4(src + (gc0 + m) * 8 + 4);
        }
    };
    auto writeA = [&](int buf) {
        unsigned char* base = lds + buf * 16384 + srow * 512;
#pragma unroll
        for (int m = 0; m < 2; ++m) {
            int gc = gc0 + m;
            uint4 w;
            w.x = f2bf(sreg[m * 2][0])     | (f2bf(sreg[m * 2][1]) << 16);
            w.y = f2bf(sreg[m * 2][2])     | (f2bf(sreg[m * 2][3]) << 16);
            w.z = f2bf(sreg[m * 2 + 1][0]) | (f2bf(sreg[m * 2 + 1][1]) << 16);
            w.w = f2bf(sreg[m * 2 + 1][2]) | (f2bf(sreg[m * 2 + 1][3]) << 16);
            int phys = (gc & 16) | ((gc ^ (srow & 15)) & 15);
            *(uint4*)(base + phys * 16) = w;
        }
    };

    loadA(0);
    writeA(0);
    asm volatile("s_waitcnt lgkmcnt(0)" ::: "memory");
    __builtin_amdgcn_s_barrier();

    for (int t = 0; t < 8; ++t) {
        const int m0 = (tile0 + t) * 32;

        if (t < 7) loadA(t + 1);

        f32x4 acc[2][4];
#pragma unroll
        for (int i = 0; i < 2; ++i)
#pragma unroll
            for (int j = 0; j < 4; ++j)
                acc[i][j] = (f32x4){0.f, 0.f, 0.f, 0.f};

        const unsigned char* Ab = lds + (t & 1) * 16384;
#pragma unroll
        for (int kk = 0; kk < 8; ++kk) {
            int g = kk * 4 + lq;
            int phys = (g & 16) | ((g ^ l15) & 15);
            short8 af[2];
#pragma unroll
            for (int i = 0; i < 2; ++i)
                af[i] = *(const short8*)(Ab + (i * 16 + l15) * 512 + phys * 16);
#pragma unroll
            for (int i = 0; i < 2; ++i)
#pragma unroll
                for (int j = 0; j < 4; ++j)
                    acc[i][j] = __builtin_amdgcn_mfma_f32_16x16x32_bf16(bfr[kk][j], af[i], acc[i][j], 0, 0, 0);
        }

        unsigned char* Bnc = lds + 32768;
#pragma unroll
        for (int i = 0; i < 2; ++i)
#pragma unroll
            for (int j = 0; j < 4; ++j) {
                unsigned lo = f2bf(acc[i][j][0]) | (f2bf(acc[i][j][1]) << 16);
                unsigned hi = f2bf(acc[i][j][2]) | (f2bf(acc[i][j][3]) << 16);
                int nodep = i * 16 + l15;
                int colbyte = wv * 128 + j * 32 + lq * 8;
                int g = colbyte >> 4;
                int phys = (g & ~15) | ((g ^ nodep) & 15);
                *(uint2*)(Bnc + nodep * 1024 + phys * 16 + (colbyte & 15)) = make_uint2(lo, hi);
            }

        asm volatile("s_waitcnt lgkmcnt(0)" ::: "memory");
        __builtin_amdgcn_s_barrier();

        // coalesced C store, REGULAR (allocating) stores: uv must be L3-resident
        // for the edge pass (R16 showed nt uv stores cost edge +37us).
#pragma unroll
        for (int p = 0; p < 4; ++p) {
            int node = p * 8 + (tid >> 6);
            int col16 = tid & 63;
            int phys = (col16 & ~15) | ((col16 ^ node) & 15);
            uint4 w = *(const uint4*)(Bnc + node * 1024 + phys * 16);
            *(uint4*)(uv + ((size_t)(m0 + node)) * 512 + col16 * 8) = w;
        }

        if (t < 7) writeA((t + 1) & 1);

        asm volatile("s_waitcnt lgkmcnt(0)" ::: "memory");
        __builtin_amdgcn_s_barrier();
    }
}

// Edge pass v2 (proven R11): 8 edges per half-wave, 16 gathers in flight.
__global__ __launch_bounds__(256) void edge2_kernel(
    const unsigned short* __restrict__ uv,
    const int* __restrict__ pos_src, const int* __restrict__ pos_dst,
    const int* __restrict__ neg_src, const int* __restrict__ neg_dst,
    const float* __restrict__ b1, const float* __restrict__ W2,
    const float* __restrict__ b2,
    float* __restrict__ out) {

    const int tid = threadIdx.x;
    const int m = tid & 31;
    const int hw = tid >> 5;
    const int eb = blockIdx.x * 64;
    const int e0 = eb + hw * 8;
    const bool is_pos = (eb < E_EDGES);
    const int ee0 = is_pos ? e0 : e0 - E_EDGES;
    const int* __restrict__ srcp = is_pos ? pos_src : neg_src;
    const int* __restrict__ dstp = is_pos ? pos_dst : neg_dst;

    int4 sa = *(const int4*)(srcp + ee0);
    int4 sb = *(const int4*)(srcp + ee0 + 4);
    int4 da = *(const int4*)(dstp + ee0);
    int4 db = *(const int4*)(dstp + ee0 + 4);
    const int sidx[8] = {sa.x, sa.y, sa.z, sa.w, sb.x, sb.y, sb.z, sb.w};
    const int didx[8] = {da.x, da.y, da.z, da.w, db.x, db.y, db.z, db.w};

    short8 uvec[8], vvec[8];
#pragma unroll
    for (int j = 0; j < 8; ++j) {
        uvec[j] = *(const short8*)(uv + (size_t)sidx[j] * 512 + m * 8);
        vvec[j] = *(const short8*)(uv + (size_t)didx[j] * 512 + 256 + m * 8);
    }

    float b1a[8], w2a[8];
    *(float4*)&b1a[0] = *(const float4*)(b1 + m * 8);
    *(float4*)&b1a[4] = *(const float4*)(b1 + m * 8 + 4);
    *(float4*)&w2a[0] = *(const float4*)(W2 + m * 8);
    *(float4*)&w2a[4] = *(const float4*)(W2 + m * 8 + 4);
    const float b2v = b2[0];

    float p[8];
#pragma unroll
    for (int j = 0; j < 8; ++j) {
        float pp = 0.f;
#pragma unroll
        for (int i = 0; i < 8; ++i) {
            float z = bf2f((unsigned short)uvec[j][i]) + bf2f((unsigned short)vvec[j][i]) + b1a[i];
            z = fmaxf(z, 0.f);
            pp = fmaf(z, w2a[i], pp);
        }
#pragma unroll
        for (int mk = 1; mk < 32; mk <<= 1) pp += __shfl_xor(pp, mk, 64);
        p[j] = pp;
    }

    float pj = p[0];
#pragma unroll
    for (int k = 1; k < 8; ++k) if (m == k) pj = p[k];
    if (m < 8) {
        float x = pj + b2v;
        out[(size_t)e0 + m] = 1.0f / (1.0f + __expf(-x));
    }
    if (tid < 64)
        out[(size_t)(2 * E_EDGES) + eb + tid] = is_pos ? 1.0f : 0.0f;
}

// ===================== mid-tier / fallback =====================
__global__ __launch_bounds__(256) void conv_table_kernel(const float* __restrict__ t,
                                                         unsigned short* __restrict__ o) {
    int idx = blockIdx.x * 256 + threadIdx.x;
    float4 a = ((const float4*)t)[idx * 2];
    float4 b = ((const float4*)t)[idx * 2 + 1];
    uint4 w;
    w.x = f2bf(a.x) | (f2bf(a.y) << 16);
    w.y = f2bf(a.z) | (f2bf(a.w) << 16);
    w.z = f2bf(b.x) | (f2bf(b.y) << 16);
    w.w = f2bf(b.z) | (f2bf(b.w) << 16);
    ((uint4*)o)[idx] = w;
}

__global__ __launch_bounds__(256) void prep_w1t_kernel(const float* __restrict__ W1,
                                                       unsigned short* __restrict__ w1t) {
    int idx = blockIdx.x * 256 + threadIdx.x;
    int k = idx >> 8;
    int n = idx & 255;
    w1t[n * KDIM + k] = (unsigned short)f2bf(W1[idx]);
}

__global__ __launch_bounds__(256) void linkpred4_kernel(
    const unsigned short* __restrict__ tblb,
    const int* __restrict__ pos_src, const int* __restrict__ pos_dst,
    const int* __restrict__ neg_src, const int* __restrict__ neg_dst,
    const float* __restrict__ b1, const float* __restrict__ W2,
    const float* __restrict__ b2,
    const unsigned short* __restrict__ w1t,
    float* __restrict__ out) {

    __shared__ __align__(16) unsigned short Bs[64 * 512];

    const int tid = threadIdx.x;
    const int l = tid & 63;
    const int wv = tid >> 6;
    const int l15 = l & 15;
    const int lq = l >> 4;
    const int m0 = blockIdx.x * 128;
    const bool is_pos = (m0 < E_EDGES);

    int nsrc[2], ndst[2];
#pragma unroll
    for (int mt = 0; mt < 2; ++mt) {
        int m = m0 + wv * 32 + mt * 16 + l15;
        if (is_pos) { nsrc[mt] = pos_src[m];            ndst[mt] = pos_dst[m]; }
        else        { int mm = m - E_EDGES; nsrc[mt] = neg_src[mm]; ndst[mt] = neg_dst[mm]; }
    }

    auto stageB = [&](int c) {
#pragma unroll
        for (int i = 0; i < 16; ++i) {
            int lc = wv * 16 + i;
            int gc = c * 64 + lc;
            const unsigned short* g = w1t + (size_t)gc * KDIM + ((l ^ i) << 3);
            char* lp = (char*)Bs + lc * 1024;
            __builtin_amdgcn_global_load_lds(
                (const __attribute__((address_space(1))) void*)g,
                (__attribute__((address_space(3))) void*)lp, 16, 0, 0);
        }
    };

    stageB(0);
    __builtin_amdgcn_sched_barrier(0);

    short8 af[2][16];
#pragma unroll
    for (int h = 0; h < 16; ++h)
#pragma unroll
        for (int mt = 0; mt < 2; ++mt) {
            int node = (h < 8) ? nsrc[mt] : ndst[mt];
            const unsigned short* g = tblb + (size_t)node * DFEAT + (h & 7) * 32 + lq * 8;
            af[mt][h] = *(const short8*)g;
        }
    __builtin_amdgcn_sched_barrier(0);

    f32x4 acc[2][4];
#pragma unroll
    for (int mt = 0; mt < 2; ++mt)
#pragma unroll
        for (int j = 0; j < 4; ++j)
            acc[mt][j] = (f32x4){0.f, 0.f, 0.f, 0.f};
    float rowacc[2][4] = {{0.f, 0.f, 0.f, 0.f}, {0.f, 0.f, 0.f, 0.f}};

    const char* Bb = (const char*)Bs;

#pragma unroll
    for (int c = 0; c < 4; ++c) {
        if (c == 0) {
            asm volatile("s_waitcnt vmcnt(32)" ::: "memory");
        } else {
            __syncthreads();
            stageB(c);
#pragma unroll
            for (int mt = 0; mt < 2; ++mt)
#pragma unroll
                for (int j = 0; j < 4; ++j) {
                    int col = (c - 1) * 64 + j * 16 + l15;
                    float b1v = b1[col], w2v = W2[col];
#pragma unroll
                    for (int r = 0; r < 4; ++r) {
                        float hv = fmaxf(acc[mt][j][r] + b1v, 0.f);
                        rowacc[mt][r] = fmaf(hv, w2v, rowacc[mt][r]);
                    }
                    acc[mt][j] = (f32x4){0.f, 0.f, 0.f, 0.f};
                }
            asm volatile("s_waitcnt vmcnt(0)" ::: "memory");
        }
        __builtin_amdgcn_s_barrier();

        __builtin_amdgcn_s_setprio(1);
#pragma unroll
        for (int h = 0; h < 16; ++h) {
            short8 bf[4];
#pragma unroll
            for (int j = 0; j < 4; ++j) {
                int cl = j * 16 + l15;
                int phys = (h * 4 + lq) ^ l15;
                bf[j] = *(const short8*)(Bb + cl * 1024 + phys * 16);
            }
#pragma unroll
            for (int mt = 0; mt < 2; ++mt)
#pragma unroll
                for (int j = 0; j < 4; ++j)
                    acc[mt][j] = __builtin_amdgcn_mfma_f32_16x16x32_bf16(af[mt][h], bf[j], acc[mt][j], 0, 0, 0);
        }
        __builtin_amdgcn_s_setprio(0);
    }

#pragma unroll
    for (int mt = 0; mt < 2; ++mt)
#pragma unroll
        for (int j = 0; j < 4; ++j) {
            int col = 3 * 64 + j * 16 + l15;
            float b1v = b1[col], w2v = W2[col];
#pragma unroll
            for (int r = 0; r < 4; ++r) {
                float hv = fmaxf(acc[mt][j][r] + b1v, 0.f);
                rowacc[mt][r] = fmaf(hv, w2v, rowacc[mt][r]);
            }
        }

    const float b2v = b2[0];
#pragma unroll
    for (int mt = 0; mt < 2; ++mt)
#pragma unroll
        for (int r = 0; r < 4; ++r) {
            float p = rowacc[mt][r];
#pragma unroll
            for (int mk = 1; mk < 16; mk <<= 1) p += __shfl_xor(p, mk, 64);
            if (l15 == 0) {
                int m = m0 + wv * 32 + mt * 16 + lq * 4 + r;
                float sg = 1.0f / (1.0f + __expf(-(p + b2v)));
                out[(size_t)m] = sg;
                out[(size_t)(2 * E_EDGES) + m] = is_pos ? 1.0f : 0.0f;
            }
        }
}

__global__ __launch_bounds__(256) void linkpred_fb_kernel(
    const float* __restrict__ table,
    const int* __restrict__ pos_src, const int* __restrict__ pos_dst,
    const int* __restrict__ neg_src, const int* __restrict__ neg_dst,
    const float* __restrict__ b1, const float* __restrict__ W2,
    const float* __restrict__ b2,
    const unsigned short* __restrict__ w1t,
    float* __restrict__ out) {

    __shared__ __align__(16) unsigned short As[2][64 * 64];
    __shared__ int sIdx[64], dIdx[64];
    __shared__ float wpart[4][64];

    const int tid = threadIdx.x;
    const int l = tid & 63;
    const int wv = tid >> 6;
    const int m0 = blockIdx.x * 64;

    if (tid < 64) {
        int m = m0 + tid;
        int si, di;
        if (m < E_EDGES) { si = pos_src[m];            di = pos_dst[m]; }
        else             { si = neg_src[m - E_EDGES];  di = neg_dst[m - E_EDGES]; }
        sIdx[tid] = si;
        dIdx[tid] = di;
    }

    float b1v[4], w2v[4];
#pragma unroll
    for (int j = 0; j < 4; j++) {
        int n = wv * 64 + j * 16 + (l & 15);
        b1v[j] = b1[n];
        w2v[j] = W2[n];
    }

    __syncthreads();

    const int e0 = tid >> 3;
    const int q  = tid & 7;
    const int e1 = e0 + 32;

    auto pack_write = [&](int buf, int e, const float4& x, const float4& y) {
        uint4 w;
        w.x = f2bf(x.x) | (f2bf(x.y) << 16);
        w.y = f2bf(x.z) | (f2bf(x.w) << 16);
        w.z = f2bf(y.x) | (f2bf(y.y) << 16);
        w.w = f2bf(y.z) | (f2bf(y.w) << 16);
        int byte = e * 128 + q * 16;
        byte ^= (e & 7) << 4;
        *(uint4*)((char*)(&As[buf][0]) + byte) = w;
    };

    {
        const float* p0 = table + (size_t)sIdx[e0] * DFEAT + q * 8;
        const float* p1 = table + (size_t)sIdx[e1] * DFEAT + q * 8;
        float4 a0 = *(const float4*)p0, a1 = *(const float4*)(p0 + 4);
        float4 c0 = *(const float4*)p1, c1 = *(const float4*)(p1 + 4);
        pack_write(0, e0, a0, a1);
        pack_write(0, e1, c0, c1);
    }
    __syncthreads();

    f32x4 acc[4][4];
#pragma unroll
    for (int i = 0; i < 4; i++)
#pragma unroll
        for (int j = 0; j < 4; j++)
            acc[i][j] = (f32x4){0.f, 0.f, 0.f, 0.f};

    for (int s = 0; s < 8; s++) {
        float4 a0, a1, c0, c1;
        if (s < 7) {
            int sn = s + 1;
            const int* idxA = (sn < 4) ? sIdx : dIdx;
            int cb = (sn & 3) * 64 + q * 8;
            const float* p0 = table + (size_t)idxA[e0] * DFEAT + cb;
            const float* p1 = table + (size_t)idxA[e1] * DFEAT + cb;
            a0 = *(const float4*)p0; a1 = *(const float4*)(p0 + 4);
            c0 = *(const float4*)p1; c1 = *(const float4*)(p1 + 4);
        }

        const int cur = s & 1;
        const char* Abase = (const char*)(&As[cur][0]);
#pragma unroll
        for (int h = 0; h < 2; h++) {
            short8 af[4], bf[4];
#pragma unroll
            for (int i = 0; i < 4; i++) {
                int row = i * 16 + (l & 15);
                int byte = row * 128 + h * 64 + ((l >> 4) << 4);
                byte ^= (l & 7) << 4;
                af[i] = *(const short8*)(Abase + byte);
            }
#pragma unroll
            for (int j = 0; j < 4; j++) {
                int col = wv * 64 + j * 16 + (l & 15);
                int koff = s * 64 + h * 32 + ((l >> 4) << 3);
                bf[j] = *(const short8*)(w1t + col * KDIM + koff);
            }
#pragma unroll
            for (int i = 0; i < 4; i++)
#pragma unroll
                for (int j = 0; j < 4; j++)
                    acc[i][j] = __builtin_amdgcn_mfma_f32_16x16x32_bf16(af[i], bf[j], acc[i][j], 0, 0, 0);
        }

        if (s < 7) {
            pack_write((s + 1) & 1, e0, a0, a1);
            pack_write((s + 1) & 1, e1, c0, c1);
        }
        __syncthreads();
    }

    float part[16];
#pragma unroll
    for (int i = 0; i < 4; i++) {
#pragma unroll
        for (int r = 0; r < 4; r++) {
            float p = 0.f;
#pragma unroll
            for (int j = 0; j < 4; j++) {
                float hv = acc[i][j][r] + b1v[j];
                hv = fmaxf(hv, 0.f);
                p = fmaf(hv, w2v[j], p);
            }
#pragma unroll
            for (int mk = 1; mk < 16; mk <<= 1) p += __shfl_xor(p, mk, 64);
            part[i * 4 + r] = p;
        }
    }
    if ((l & 15) == 0) {
        int g = l >> 4;
#pragma unroll
        for (int i = 0; i < 4; i++)
#pragma unroll
            for (int r = 0; r < 4; r++)
                wpart[wv][i * 16 + g * 4 + r] = part[i * 4 + r];
    }
    __syncthreads();

    if (tid < 64) {
        float x = wpart[0][tid] + wpart[1][tid] + wpart[2][tid] + wpart[3][tid] + b2[0];
        float sg = 1.0f / (1.0f + __expf(-x));
        out[(size_t)m0 + tid] = sg;
        out[(size_t)(2 * E_EDGES) + m0 + tid] = (m0 < E_EDGES) ? 1.0f : 0.0f;
    }
}

extern "C" void kernel_launch(void* const* d_in, const int* in_sizes, int n_in,
                              void* d_out, int out_size, void* d_ws, size_t ws_size,
                              hipStream_t stream) {
    const float* table = (const float*)d_in[0];
    const int* ps = (const int*)d_in[1];
    const int* pd = (const int*)d_in[2];
    const int* ns = (const int*)d_in[3];
    const int* nd = (const int*)d_in[4];
    const float* W1 = (const float*)d_in[5];
    const float* b1 = (const float*)d_in[6];
    const float* W2 = (const float*)d_in[7];
    const float* b2 = (const float*)d_in[8];
    float* out = (float*)d_out;

    const size_t wB_bytes  = (size_t)KDIM * 256 * 2;           // 262,144
    const size_t uv_bytes  = (size_t)NNODES * KDIM * 2;        // 134,217,728
    const size_t tbl_bytes = (size_t)NNODES * DFEAT * 2;       // 67,108,864
    const size_t w1t_bytes = (size_t)256 * KDIM * 2;           // 262,144

    if (ws_size >= wB_bytes + uv_bytes) {
        unsigned short* wB2 = (unsigned short*)d_ws;
        unsigned short* uv = (unsigned short*)((char*)d_ws + wB_bytes);
        hipLaunchKernelGGL(prep_wB2_kernel, dim3(512), dim3(256), 0, stream, W1, wB2);
        hipLaunchKernelGGL(gemm_uv5_kernel, dim3(512), dim3(512), 0, stream, table, wB2, uv);
        hipLaunchKernelGGL(edge2_kernel, dim3(8192), dim3(256), 0, stream,
                           uv, ps, pd, ns, nd, b1, W2, b2, out);
    } else if (ws_size >= tbl_bytes + w1t_bytes) {
        unsigned short* tblb = (unsigned short*)d_ws;
        unsigned short* w1t = (unsigned short*)((char*)d_ws + tbl_bytes);
        hipLaunchKernelGGL(conv_table_kernel, dim3(16384), dim3(256), 0, stream, table, tblb);
        hipLaunchKernelGGL(prep_w1t_kernel, dim3(512), dim3(256), 0, stream, W1, w1t);
        hipLaunchKernelGGL(linkpred4_kernel, dim3(4096), dim3(256), 0, stream,
                           tblb, ps, pd, ns, nd, b1, W2, b2, w1t, out);
    } else {
        unsigned short* w1t = (unsigned short*)d_ws;
        hipLaunchKernelGGL(prep_w1t_kernel, dim3(512), dim3(256), 0, stream, W1, w1t);
        hipLaunchKernelGGL(linkpred_fb_kernel, dim3(8192), dim3(256), 0, stream,
                           table, ps, pd, ns, nd, b1, W2, b2, w1t, out);
    }
}

// Round 18
// 140.642 us; speedup vs baseline: 1.0942x; 1.0942x over previous
//
#include <hip/hip_runtime.h>
#include <hip/hip_bf16.h>
#include <stdint.h>

#define E_EDGES 262144
#define DFEAT 256
#define KDIM 512
#define NNODES 131072

typedef __attribute__((ext_vector_type(8))) short short8;
typedef __attribute__((ext_vector_type(4))) float f32x4;

static __device__ __forceinline__ unsigned f2bf(float x) {
    unsigned u = __float_as_uint(x);
    u += 0x7fffu + ((u >> 16) & 1u);   // RNE
    return u >> 16;
}
static __device__ __forceinline__ float bf2f(unsigned short s) {
    return __uint_as_float(((unsigned)s) << 16);
}

// ===================== fast path =====================
// wB2: k-slab-major repack (proven R9). wB2[((k>>3)*512 + n)*8 + (k&7)]
__global__ __launch_bounds__(256) void prep_wB2_kernel(const float* __restrict__ W1,
                                                       unsigned short* __restrict__ wB2) {
    int idx = blockIdx.x * 256 + threadIdx.x;   // 131072
    int n = idx >> 8;
    int k = idx & 255;
    int srow = k + ((n >= 256) ? 256 : 0);
    wB2[((size_t)(k >> 3) * 512 + n) * 8 + (k & 7)] = (unsigned short)f2bf(W1[srow * 256 + (n & 255)]);
}

// Persistent-pipeline GEMM (exact R12 config — best measured: total 140.7us).
// 512 blocks x 512 threads x 8 tiles. B fully in registers (tile-invariant);
// A reg-staged issue-early / convert+ds_write-late; lgkm-only barrier waits so
// A-loads stay in flight across barriers; C via swizzled LDS bounce -> 1KB
// coalesced allocating stores (uv L3-residency feeds the edge pass).
__global__ __launch_bounds__(512, 2) void gemm_uv5_kernel(const float* __restrict__ table,
                                                          const unsigned short* __restrict__ wB2,
                                                          unsigned short* __restrict__ uv) {
    __shared__ __align__(16) unsigned char lds[65536];

    const int tid = threadIdx.x;
    const int l = tid & 63;
    const int wv = tid >> 6;
    const int l15 = l & 15;
    const int lq = l >> 4;

    short8 bfr[8][4];
#pragma unroll
    for (int kk = 0; kk < 8; ++kk)
#pragma unroll
        for (int j = 0; j < 4; ++j) {
            int col = wv * 64 + j * 16 + l15;
            bfr[kk][j] = *(const short8*)(wB2 + ((size_t)(kk * 4 + lq) * 512 + col) * 8);
        }

    const int srow = tid >> 4;
    const int gc0 = (tid & 15) * 2;
    const int tile0 = blockIdx.x * 8;

    float4 sreg[4];
    auto loadA = [&](int t) {
        const float* src = table + (size_t)(tile0 + t) * 32 * DFEAT + (size_t)srow * DFEAT;
#pragma unroll
        for (int m = 0; m < 2; ++m) {
            sreg[m * 2]     = *(const float4*)(src + (gc0 + m) * 8);
            sreg[m * 2 + 1] = *(const float4*)(src + (gc0 + m) * 8 + 4);
        }
    };
    auto writeA = [&](int buf) {
        unsigned char* base = lds + buf * 16384 + srow * 512;
#pragma unroll
        for (int m = 0; m < 2; ++m) {
            int gc = gc0 + m;
            uint4 w;
            w.x = f2bf(sreg[m * 2].x)     | (f2bf(sreg[m * 2].y) << 16);
            w.y = f2bf(sreg[m * 2].z)     | (f2bf(sreg[m * 2].w) << 16);
            w.z = f2bf(sreg[m * 2 + 1].x) | (f2bf(sreg[m * 2 + 1].y) << 16);
            w.w = f2bf(sreg[m * 2 + 1].z) | (f2bf(sreg[m * 2 + 1].w) << 16);
            int phys = (gc & 16) | ((gc ^ (srow & 15)) & 15);
            *(uint4*)(base + phys * 16) = w;
        }
    };

    loadA(0);
    writeA(0);
    asm volatile("s_waitcnt lgkmcnt(0)" ::: "memory");
    __builtin_amdgcn_s_barrier();

    for (int t = 0; t < 8; ++t) {
        const int m0 = (tile0 + t) * 32;

        if (t < 7) loadA(t + 1);

        f32x4 acc[2][4];
#pragma unroll
        for (int i = 0; i < 2; ++i)
#pragma unroll
            for (int j = 0; j < 4; ++j)
                acc[i][j] = (f32x4){0.f, 0.f, 0.f, 0.f};

        const unsigned char* Ab = lds + (t & 1) * 16384;
#pragma unroll
        for (int kk = 0; kk < 8; ++kk) {
            int g = kk * 4 + lq;
            int phys = (g & 16) | ((g ^ l15) & 15);
            short8 af[2];
#pragma unroll
            for (int i = 0; i < 2; ++i)
                af[i] = *(const short8*)(Ab + (i * 16 + l15) * 512 + phys * 16);
#pragma unroll
            for (int i = 0; i < 2; ++i)
#pragma unroll
                for (int j = 0; j < 4; ++j)
                    acc[i][j] = __builtin_amdgcn_mfma_f32_16x16x32_bf16(bfr[kk][j], af[i], acc[i][j], 0, 0, 0);
        }

        unsigned char* Bnc = lds + 32768;
#pragma unroll
        for (int i = 0; i < 2; ++i)
#pragma unroll
            for (int j = 0; j < 4; ++j) {
                unsigned lo = f2bf(acc[i][j][0]) | (f2bf(acc[i][j][1]) << 16);
                unsigned hi = f2bf(acc[i][j][2]) | (f2bf(acc[i][j][3]) << 16);
                int nodep = i * 16 + l15;
                int colbyte = wv * 128 + j * 32 + lq * 8;
                int g = colbyte >> 4;
                int phys = (g & ~15) | ((g ^ nodep) & 15);
                *(uint2*)(Bnc + nodep * 1024 + phys * 16 + (colbyte & 15)) = make_uint2(lo, hi);
            }

        asm volatile("s_waitcnt lgkmcnt(0)" ::: "memory");
        __builtin_amdgcn_s_barrier();

#pragma unroll
        for (int p = 0; p < 4; ++p) {
            int node = p * 8 + (tid >> 6);
            int col16 = tid & 63;
            int phys = (col16 & ~15) | ((col16 ^ node) & 15);
            uint4 w = *(const uint4*)(Bnc + node * 1024 + phys * 16);
            *(uint4*)(uv + ((size_t)(m0 + node)) * 512 + col16 * 8) = w;
        }

        if (t < 7) writeA((t + 1) & 1);

        asm volatile("s_waitcnt lgkmcnt(0)" ::: "memory");
        __builtin_amdgcn_s_barrier();
    }
}

// Edge pass v2 (proven R11): 8 edges per half-wave, 16 gathers in flight.
__global__ __launch_bounds__(256) void edge2_kernel(
    const unsigned short* __restrict__ uv,
    const int* __restrict__ pos_src, const int* __restrict__ pos_dst,
    const int* __restrict__ neg_src, const int* __restrict__ neg_dst,
    const float* __restrict__ b1, const float* __restrict__ W2,
    const float* __restrict__ b2,
    float* __restrict__ out) {

    const int tid = threadIdx.x;
    const int m = tid & 31;
    const int hw = tid >> 5;
    const int eb = blockIdx.x * 64;
    const int e0 = eb + hw * 8;
    const bool is_pos = (eb < E_EDGES);
    const int ee0 = is_pos ? e0 : e0 - E_EDGES;
    const int* __restrict__ srcp = is_pos ? pos_src : neg_src;
    const int* __restrict__ dstp = is_pos ? pos_dst : neg_dst;

    int4 sa = *(const int4*)(srcp + ee0);
    int4 sb = *(const int4*)(srcp + ee0 + 4);
    int4 da = *(const int4*)(dstp + ee0);
    int4 db = *(const int4*)(dstp + ee0 + 4);
    const int sidx[8] = {sa.x, sa.y, sa.z, sa.w, sb.x, sb.y, sb.z, sb.w};
    const int didx[8] = {da.x, da.y, da.z, da.w, db.x, db.y, db.z, db.w};

    short8 uvec[8], vvec[8];
#pragma unroll
    for (int j = 0; j < 8; ++j) {
        uvec[j] = *(const short8*)(uv + (size_t)sidx[j] * 512 + m * 8);
        vvec[j] = *(const short8*)(uv + (size_t)didx[j] * 512 + 256 + m * 8);
    }

    float b1a[8], w2a[8];
    *(float4*)&b1a[0] = *(const float4*)(b1 + m * 8);
    *(float4*)&b1a[4] = *(const float4*)(b1 + m * 8 + 4);
    *(float4*)&w2a[0] = *(const float4*)(W2 + m * 8);
    *(float4*)&w2a[4] = *(const float4*)(W2 + m * 8 + 4);
    const float b2v = b2[0];

    float p[8];
#pragma unroll
    for (int j = 0; j < 8; ++j) {
        float pp = 0.f;
#pragma unroll
        for (int i = 0; i < 8; ++i) {
            float z = bf2f((unsigned short)uvec[j][i]) + bf2f((unsigned short)vvec[j][i]) + b1a[i];
            z = fmaxf(z, 0.f);
            pp = fmaf(z, w2a[i], pp);
        }
#pragma unroll
        for (int mk = 1; mk < 32; mk <<= 1) pp += __shfl_xor(pp, mk, 64);
        p[j] = pp;
    }

    float pj = p[0];
#pragma unroll
    for (int k = 1; k < 8; ++k) if (m == k) pj = p[k];
    if (m < 8) {
        float x = pj + b2v;
        out[(size_t)e0 + m] = 1.0f / (1.0f + __expf(-x));
    }
    if (tid < 64)
        out[(size_t)(2 * E_EDGES) + eb + tid] = is_pos ? 1.0f : 0.0f;
}

// ===================== mid-tier / fallback =====================
__global__ __launch_bounds__(256) void conv_table_kernel(const float* __restrict__ t,
                                                         unsigned short* __restrict__ o) {
    int idx = blockIdx.x * 256 + threadIdx.x;
    float4 a = ((const float4*)t)[idx * 2];
    float4 b = ((const float4*)t)[idx * 2 + 1];
    uint4 w;
    w.x = f2bf(a.x) | (f2bf(a.y) << 16);
    w.y = f2bf(a.z) | (f2bf(a.w) << 16);
    w.z = f2bf(b.x) | (f2bf(b.y) << 16);
    w.w = f2bf(b.z) | (f2bf(b.w) << 16);
    ((uint4*)o)[idx] = w;
}

__global__ __launch_bounds__(256) void prep_w1t_kernel(const float* __restrict__ W1,
                                                       unsigned short* __restrict__ w1t) {
    int idx = blockIdx.x * 256 + threadIdx.x;
    int k = idx >> 8;
    int n = idx & 255;
    w1t[n * KDIM + k] = (unsigned short)f2bf(W1[idx]);
}

__global__ __launch_bounds__(256) void linkpred4_kernel(
    const unsigned short* __restrict__ tblb,
    const int* __restrict__ pos_src, const int* __restrict__ pos_dst,
    const int* __restrict__ neg_src, const int* __restrict__ neg_dst,
    const float* __restrict__ b1, const float* __restrict__ W2,
    const float* __restrict__ b2,
    const unsigned short* __restrict__ w1t,
    float* __restrict__ out) {

    __shared__ __align__(16) unsigned short Bs[64 * 512];

    const int tid = threadIdx.x;
    const int l = tid & 63;
    const int wv = tid >> 6;
    const int l15 = l & 15;
    const int lq = l >> 4;
    const int m0 = blockIdx.x * 128;
    const bool is_pos = (m0 < E_EDGES);

    int nsrc[2], ndst[2];
#pragma unroll
    for (int mt = 0; mt < 2; ++mt) {
        int m = m0 + wv * 32 + mt * 16 + l15;
        if (is_pos) { nsrc[mt] = pos_src[m];            ndst[mt] = pos_dst[m]; }
        else        { int mm = m - E_EDGES; nsrc[mt] = neg_src[mm]; ndst[mt] = neg_dst[mm]; }
    }

    auto stageB = [&](int c) {
#pragma unroll
        for (int i = 0; i < 16; ++i) {
            int lc = wv * 16 + i;
            int gc = c * 64 + lc;
            const unsigned short* g = w1t + (size_t)gc * KDIM + ((l ^ i) << 3);
            char* lp = (char*)Bs + lc * 1024;
            __builtin_amdgcn_global_load_lds(
                (const __attribute__((address_space(1))) void*)g,
                (__attribute__((address_space(3))) void*)lp, 16, 0, 0);
        }
    };

    stageB(0);
    __builtin_amdgcn_sched_barrier(0);

    short8 af[2][16];
#pragma unroll
    for (int h = 0; h < 16; ++h)
#pragma unroll
        for (int mt = 0; mt < 2; ++mt) {
            int node = (h < 8) ? nsrc[mt] : ndst[mt];
            const unsigned short* g = tblb + (size_t)node * DFEAT + (h & 7) * 32 + lq * 8;
            af[mt][h] = *(const short8*)g;
        }
    __builtin_amdgcn_sched_barrier(0);

    f32x4 acc[2][4];
#pragma unroll
    for (int mt = 0; mt < 2; ++mt)
#pragma unroll
        for (int j = 0; j < 4; ++j)
            acc[mt][j] = (f32x4){0.f, 0.f, 0.f, 0.f};
    float rowacc[2][4] = {{0.f, 0.f, 0.f, 0.f}, {0.f, 0.f, 0.f, 0.f}};

    const char* Bb = (const char*)Bs;

#pragma unroll
    for (int c = 0; c < 4; ++c) {
        if (c == 0) {
            asm volatile("s_waitcnt vmcnt(32)" ::: "memory");
        } else {
            __syncthreads();
            stageB(c);
#pragma unroll
            for (int mt = 0; mt < 2; ++mt)
#pragma unroll
                for (int j = 0; j < 4; ++j) {
                    int col = (c - 1) * 64 + j * 16 + l15;
                    float b1v = b1[col], w2v = W2[col];
#pragma unroll
                    for (int r = 0; r < 4; ++r) {
                        float hv = fmaxf(acc[mt][j][r] + b1v, 0.f);
                        rowacc[mt][r] = fmaf(hv, w2v, rowacc[mt][r]);
                    }
                    acc[mt][j] = (f32x4){0.f, 0.f, 0.f, 0.f};
                }
            asm volatile("s_waitcnt vmcnt(0)" ::: "memory");
        }
        __builtin_amdgcn_s_barrier();

        __builtin_amdgcn_s_setprio(1);
#pragma unroll
        for (int h = 0; h < 16; ++h) {
            short8 bf[4];
#pragma unroll
            for (int j = 0; j < 4; ++j) {
                int cl = j * 16 + l15;
                int phys = (h * 4 + lq) ^ l15;
                bf[j] = *(const short8*)(Bb + cl * 1024 + phys * 16);
            }
#pragma unroll
            for (int mt = 0; mt < 2; ++mt)
#pragma unroll
                for (int j = 0; j < 4; ++j)
                    acc[mt][j] = __builtin_amdgcn_mfma_f32_16x16x32_bf16(af[mt][h], bf[j], acc[mt][j], 0, 0, 0);
        }
        __builtin_amdgcn_s_setprio(0);
    }

#pragma unroll
    for (int mt = 0; mt < 2; ++mt)
#pragma unroll
        for (int j = 0; j < 4; ++j) {
            int col = 3 * 64 + j * 16 + l15;
            float b1v = b1[col], w2v = W2[col];
#pragma unroll
            for (int r = 0; r < 4; ++r) {
                float hv = fmaxf(acc[mt][j][r] + b1v, 0.f);
                rowacc[mt][r] = fmaf(hv, w2v, rowacc[mt][r]);
            }
        }

    const float b2v = b2[0];
#pragma unroll
    for (int mt = 0; mt < 2; ++mt)
#pragma unroll
        for (int r = 0; r < 4; ++r) {
            float p = rowacc[mt][r];
#pragma unroll
            for (int mk = 1; mk < 16; mk <<= 1) p += __shfl_xor(p, mk, 64);
            if (l15 == 0) {
                int m = m0 + wv * 32 + mt * 16 + lq * 4 + r;
                float sg = 1.0f / (1.0f + __expf(-(p + b2v)));
                out[(size_t)m] = sg;
                out[(size_t)(2 * E_EDGES) + m] = is_pos ? 1.0f : 0.0f;
            }
        }
}

__global__ __launch_bounds__(256) void linkpred_fb_kernel(
    const float* __restrict__ table,
    const int* __restrict__ pos_src, const int* __restrict__ pos_dst,
    const int* __restrict__ neg_src, const int* __restrict__ neg_dst,
    const float* __restrict__ b1, const float* __restrict__ W2,
    const float* __restrict__ b2,
    const unsigned short* __restrict__ w1t,
    float* __restrict__ out) {

    __shared__ __align__(16) unsigned short As[2][64 * 64];
    __shared__ int sIdx[64], dIdx[64];
    __shared__ float wpart[4][64];

    const int tid = threadIdx.x;
    const int l = tid & 63;
    const int wv = tid >> 6;
    const int m0 = blockIdx.x * 64;

    if (tid < 64) {
        int m = m0 + tid;
        int si, di;
        if (m < E_EDGES) { si = pos_src[m];            di = pos_dst[m]; }
        else             { si = neg_src[m - E_EDGES];  di = neg_dst[m - E_EDGES]; }
        sIdx[tid] = si;
        dIdx[tid] = di;
    }

    float b1v[4], w2v[4];
#pragma unroll
    for (int j = 0; j < 4; j++) {
        int n = wv * 64 + j * 16 + (l & 15);
        b1v[j] = b1[n];
        w2v[j] = W2[n];
    }

    __syncthreads();

    const int e0 = tid >> 3;
    const int q  = tid & 7;
    const int e1 = e0 + 32;

    auto pack_write = [&](int buf, int e, const float4& x, const float4& y) {
        uint4 w;
        w.x = f2bf(x.x) | (f2bf(x.y) << 16);
        w.y = f2bf(x.z) | (f2bf(x.w) << 16);
        w.z = f2bf(y.x) | (f2bf(y.y) << 16);
        w.w = f2bf(y.z) | (f2bf(y.w) << 16);
        int byte = e * 128 + q * 16;
        byte ^= (e & 7) << 4;
        *(uint4*)((char*)(&As[buf][0]) + byte) = w;
    };

    {
        const float* p0 = table + (size_t)sIdx[e0] * DFEAT + q * 8;
        const float* p1 = table + (size_t)sIdx[e1] * DFEAT + q * 8;
        float4 a0 = *(const float4*)p0, a1 = *(const float4*)(p0 + 4);
        float4 c0 = *(const float4*)p1, c1 = *(const float4*)(p1 + 4);
        pack_write(0, e0, a0, a1);
        pack_write(0, e1, c0, c1);
    }
    __syncthreads();

    f32x4 acc[4][4];
#pragma unroll
    for (int i = 0; i < 4; i++)
#pragma unroll
        for (int j = 0; j < 4; j++)
            acc[i][j] = (f32x4){0.f, 0.f, 0.f, 0.f};

    for (int s = 0; s < 8; s++) {
        float4 a0, a1, c0, c1;
        if (s < 7) {
            int sn = s + 1;
            const int* idxA = (sn < 4) ? sIdx : dIdx;
            int cb = (sn & 3) * 64 + q * 8;
            const float* p0 = table + (size_t)idxA[e0] * DFEAT + cb;
            const float* p1 = table + (size_t)idxA[e1] * DFEAT + cb;
            a0 = *(const float4*)p0; a1 = *(const float4*)(p0 + 4);
            c0 = *(const float4*)p1; c1 = *(const float4*)(p1 + 4);
        }

        const int cur = s & 1;
        const char* Abase = (const char*)(&As[cur][0]);
#pragma unroll
        for (int h = 0; h < 2; h++) {
            short8 af[4], bf[4];
#pragma unroll
            for (int i = 0; i < 4; i++) {
                int row = i * 16 + (l & 15);
                int byte = row * 128 + h * 64 + ((l >> 4) << 4);
                byte ^= (l & 7) << 4;
                af[i] = *(const short8*)(Abase + byte);
            }
#pragma unroll
            for (int j = 0; j < 4; j++) {
                int col = wv * 64 + j * 16 + (l & 15);
                int koff = s * 64 + h * 32 + ((l >> 4) << 3);
                bf[j] = *(const short8*)(w1t + col * KDIM + koff);
            }
#pragma unroll
            for (int i = 0; i < 4; i++)
#pragma unroll
                for (int j = 0; j < 4; j++)
                    acc[i][j] = __builtin_amdgcn_mfma_f32_16x16x32_bf16(af[i], bf[j], acc[i][j], 0, 0, 0);
        }

        if (s < 7) {
            pack_write((s + 1) & 1, e0, a0, a1);
            pack_write((s + 1) & 1, e1, c0, c1);
        }
        __syncthreads();
    }

    float part[16];
#pragma unroll
    for (int i = 0; i < 4; i++) {
#pragma unroll
        for (int r = 0; r < 4; r++) {
            float p = 0.f;
#pragma unroll
            for (int j = 0; j < 4; j++) {
                float hv = acc[i][j][r] + b1v[j];
                hv = fmaxf(hv, 0.f);
                p = fmaf(hv, w2v[j], p);
            }
#pragma unroll
            for (int mk = 1; mk < 16; mk <<= 1) p += __shfl_xor(p, mk, 64);
            part[i * 4 + r] = p;
        }
    }
    if ((l & 15) == 0) {
        int g = l >> 4;
#pragma unroll
        for (int i = 0; i < 4; i++)
#pragma unroll
            for (int r = 0; r < 4; r++)
                wpart[wv][i * 16 + g * 4 + r] = part[i * 4 + r];
    }
    __syncthreads();

    if (tid < 64) {
        float x = wpart[0][tid] + wpart[1][tid] + wpart[2][tid] + wpart[3][tid] + b2[0];
        float sg = 1.0f / (1.0f + __expf(-x));
        out[(size_t)m0 + tid] = sg;
        out[(size_t)(2 * E_EDGES) + m0 + tid] = (m0 < E_EDGES) ? 1.0f : 0.0f;
    }
}

extern "C" void kernel_launch(void* const* d_in, const int* in_sizes, int n_in,
                              void* d_out, int out_size, void* d_ws, size_t ws_size,
                              hipStream_t stream) {
    const float* table = (const float*)d_in[0];
    const int* ps = (const int*)d_in[1];
    const int* pd = (const int*)d_in[2];
    const int* ns = (const int*)d_in[3];
    const int* nd = (const int*)d_in[4];
    const float* W1 = (const float*)d_in[5];
    const float* b1 = (const float*)d_in[6];
    const float* W2 = (const float*)d_in[7];
    const float* b2 = (const float*)d_in[8];
    float* out = (float*)d_out;

    const size_t wB_bytes  = (size_t)KDIM * 256 * 2;           // 262,144
    const size_t uv_bytes  = (size_t)NNODES * KDIM * 2;        // 134,217,728
    const size_t tbl_bytes = (size_t)NNODES * DFEAT * 2;       // 67,108,864
    const size_t w1t_bytes = (size_t)256 * KDIM * 2;           // 262,144

    if (ws_size >= wB_bytes + uv_bytes) {
        unsigned short* wB2 = (unsigned short*)d_ws;
        unsigned short* uv = (unsigned short*)((char*)d_ws + wB_bytes);
        hipLaunchKernelGGL(prep_wB2_kernel, dim3(512), dim3(256), 0, stream, W1, wB2);
        hipLaunchKernelGGL(gemm_uv5_kernel, dim3(512), dim3(512), 0, stream, table, wB2, uv);
        hipLaunchKernelGGL(edge2_kernel, dim3(8192), dim3(256), 0, stream,
                           uv, ps, pd, ns, nd, b1, W2, b2, out);
    } else if (ws_size >= tbl_bytes + w1t_bytes) {
        unsigned short* tblb = (unsigned short*)d_ws;
        unsigned short* w1t = (unsigned short*)((char*)d_ws + tbl_bytes);
        hipLaunchKernelGGL(conv_table_kernel, dim3(16384), dim3(256), 0, stream, table, tblb);
        hipLaunchKernelGGL(prep_w1t_kernel, dim3(512), dim3(256), 0, stream, W1, w1t);
        hipLaunchKernelGGL(linkpred4_kernel, dim3(4096), dim3(256), 0, stream,
                           tblb, ps, pd, ns, nd, b1, W2, b2, w1t, out);
    } else {
        unsigned short* w1t = (unsigned short*)d_ws;
        hipLaunchKernelGGL(prep_w1t_kernel, dim3(512), dim3(256), 0, stream, W1, w1t);
        hipLaunchKernelGGL(linkpred_fb_kernel, dim3(8192), dim3(256), 0, stream,
                           table, ps, pd, ns, nd, b1, W2, b2, w1t, out);
    }
}